// Round 2
// baseline (149.603 us; speedup 1.0000x reference)
//
#include <hip/hip_runtime.h>
#include <hip/hip_bf16.h>
#include <cstdint>

typedef unsigned short u16;
typedef __bf16 bf16x8 __attribute__((ext_vector_type(8)));
typedef float f32x4 __attribute__((ext_vector_type(4)));
typedef u16 u16x8 __attribute__((ext_vector_type(8)));

// Sizes fixed by reference: B=8, S=2048, I=256, H=256, M=1024
#define NX 4194304L   // key elems (16384*256)

__device__ __forceinline__ u16 f2bf(float f) {
  union { float f; uint32_t u; } v; v.f = f;
  uint32_t r = v.u + 0x7fffu + ((v.u >> 16) & 1u);
  return (u16)(r >> 16);
}

__device__ __forceinline__ u16x8 cvt8(float4 a, float4 b) {
  u16x8 o;
  o[0]=f2bf(a.x); o[1]=f2bf(a.y); o[2]=f2bf(a.z); o[3]=f2bf(a.w);
  o[4]=f2bf(b.x); o[5]=f2bf(b.y); o[6]=f2bf(b.z); o[7]=f2bf(b.w);
  return o;
}

// Fused NT GEMM with in-staging fp32->bf16 conversion.
// C[M,N] = op(A[M,K] * B[N,K]^T).  B always fp32; A fp32 or bf16.
// 128x128 tile, BK=32, 256 threads (2x2 waves of 64x64), 16x16x32 bf16 MFMA.
// Staging: thread t loads 16 contiguous K-elems of row (t>>1), col (t&1)*16,
// register-double-buffered across K-iterations (prefetch overlaps MFMA).
template<bool A_BF16, bool RELU, bool STORE_BF16>
__global__ __launch_bounds__(256, 2)
void gemm_fused(const void* __restrict__ Ap, const float* __restrict__ Bp,
                float* __restrict__ C, u16* __restrict__ Cbf,
                int N, int K,
                long sA_batch, long sB_batch, long sC_batch)
{
  __shared__ __align__(16) u16 sA[128 * 32];   // 8 KB
  __shared__ __align__(16) u16 sB[128 * 32];   // 8 KB
  const int tid  = threadIdx.x;
  const int wave = tid >> 6;
  const int lane = tid & 63;
  const int quad = lane >> 4;
  const int r    = lane & 15;
  const int wm   = wave >> 1;
  const int wn   = wave & 1;
  const int bm   = blockIdx.y * 128;
  const int bn   = blockIdx.x * 128;
  const int batch = blockIdx.z;

  const int rowL = tid >> 1;        // 0..127 staging row
  const int colL = (tid & 1) * 16;  // 0 or 16 (K-elems within BK=32)

  const float* Bg = Bp + (long)batch * sB_batch + (long)(bn + rowL) * K + colL;
  const float* Af = nullptr;
  const u16*   Ah = nullptr;
  if (A_BF16) Ah = (const u16*)Ap + (long)batch * sA_batch + (long)(bm + rowL) * K + colL;
  else        Af = (const float*)Ap + (long)batch * sA_batch + (long)(bm + rowL) * K + colL;

  u16* dA = sA + rowL * 32 + colL;
  u16* dB = sB + rowL * 32 + colL;

  f32x4 acc[4][4];
  #pragma unroll
  for (int i = 0; i < 4; i++)
    #pragma unroll
    for (int j = 0; j < 4; j++)
      acc[i][j] = f32x4{0.f, 0.f, 0.f, 0.f};

  // prefetch registers
  float4 ra[4], rb[4];
  uint4  ha[2];

  // prologue loads (kt = 0)
  if (A_BF16) {
    ha[0] = *(const uint4*)(Ah);
    ha[1] = *(const uint4*)(Ah + 8);
  } else {
    ra[0] = *(const float4*)(Af);
    ra[1] = *(const float4*)(Af + 4);
    ra[2] = *(const float4*)(Af + 8);
    ra[3] = *(const float4*)(Af + 12);
  }
  rb[0] = *(const float4*)(Bg);
  rb[1] = *(const float4*)(Bg + 4);
  rb[2] = *(const float4*)(Bg + 8);
  rb[3] = *(const float4*)(Bg + 12);

  for (int kt = 0; kt < K; kt += 32) {
    __syncthreads();   // prior iteration's frag reads complete
    if (A_BF16) {
      *(uint4*)dA       = ha[0];
      *(uint4*)(dA + 8) = ha[1];
    } else {
      *(u16x8*)dA       = cvt8(ra[0], ra[1]);
      *(u16x8*)(dA + 8) = cvt8(ra[2], ra[3]);
    }
    *(u16x8*)dB       = cvt8(rb[0], rb[1]);
    *(u16x8*)(dB + 8) = cvt8(rb[2], rb[3]);
    __syncthreads();   // writes visible

    // prefetch next K-tile (overlaps frag reads + MFMA below)
    const int kn = kt + 32;
    if (kn < K) {
      if (A_BF16) {
        ha[0] = *(const uint4*)(Ah + kn);
        ha[1] = *(const uint4*)(Ah + kn + 8);
      } else {
        ra[0] = *(const float4*)(Af + kn);
        ra[1] = *(const float4*)(Af + kn + 4);
        ra[2] = *(const float4*)(Af + kn + 8);
        ra[3] = *(const float4*)(Af + kn + 12);
      }
      rb[0] = *(const float4*)(Bg + kn);
      rb[1] = *(const float4*)(Bg + kn + 4);
      rb[2] = *(const float4*)(Bg + kn + 8);
      rb[3] = *(const float4*)(Bg + kn + 12);
    }

    // A-frag: A[m=lane&15][k=quad*8+j]; B-frag: B^T[n=lane&15][k=quad*8+j]
    bf16x8 af[4], bf[4];
    #pragma unroll
    for (int i = 0; i < 4; i++)
      af[i] = *(const bf16x8*)(sA + (wm * 64 + i * 16 + r) * 32 + quad * 8);
    #pragma unroll
    for (int j = 0; j < 4; j++)
      bf[j] = *(const bf16x8*)(sB + (wn * 64 + j * 16 + r) * 32 + quad * 8);
    #pragma unroll
    for (int i = 0; i < 4; i++)
      #pragma unroll
      for (int j = 0; j < 4; j++)
        acc[i][j] = __builtin_amdgcn_mfma_f32_16x16x32_bf16(af[i], bf[j], acc[i][j], 0, 0, 0);
  }

  // epilogue: C/D layout col=lane&15, row=quad*4+reg (verified m89/m91)
  float* Co = C + (long)batch * sC_batch;
  u16*   Bo = STORE_BF16 ? (Cbf + (long)batch * sC_batch) : nullptr;
  #pragma unroll
  for (int i = 0; i < 4; i++) {
    #pragma unroll
    for (int j = 0; j < 4; j++) {
      #pragma unroll
      for (int reg = 0; reg < 4; reg++) {
        const int row = bm + wm * 64 + i * 16 + quad * 4 + reg;
        const int col = bn + wn * 64 + j * 16 + r;
        float v = acc[i][j][reg];
        if (RELU) v = v > 0.f ? v : 0.f;
        const long idx = (long)row * N + col;
        Co[idx] = v;
        if (STORE_BF16) Bo[idx] = f2bf(v);
      }
    }
  }
}

extern "C" void kernel_launch(void* const* d_in, const int* in_sizes, int n_in,
                              void* d_out, int out_size, void* d_ws, size_t ws_size,
                              hipStream_t stream) {
  const float* x   = (const float*)d_in[0];  // (8,2048,256) -> (16384,256)
  const float* mem = (const float*)d_in[1];  // (8,1024,256)
  const float* W   = (const float*)d_in[2];  // (256,256)
  float* out   = (float*)d_out;
  float* key_f = out;            // (16384,256) fp32
  float* val_f = out + NX;       // (8,2048,1024) fp32
  u16* key_bf  = (u16*)d_ws;     // (16384,256) bf16, 8.4 MB

  // 1) key = relu(x @ W^T): M=16384, N=256, K=256; fp32 A/B staged+converted;
  //    dual-store fp32 (d_out) + bf16 (ws)
  dim3 g1(2, 128, 1);
  gemm_fused<false, true, true><<<g1, 256, 0, stream>>>(
      (const void*)x, W, key_f, key_bf, 256, 256, 0, 0, 0);

  // 2) val_b = key_b @ mem_b^T: per batch M=2048, N=1024, K=256;
  //    A = bf16 key from ws, B = mem fp32 staged+converted
  dim3 g2(8, 16, 8);
  gemm_fused<true, false, false><<<g2, 256, 0, stream>>>(
      (const void*)key_bf, mem, val_f, nullptr, 1024, 256,
      (long)2048 * 256, (long)1024 * 256, (long)2048 * 1024);
}

// Round 3
// 138.492 us; speedup vs baseline: 1.0802x; 1.0802x over previous
//
#include <hip/hip_runtime.h>
#include <cstdint>

typedef unsigned short u16;
typedef __bf16 bf16x8 __attribute__((ext_vector_type(8)));
typedef float f32x4 __attribute__((ext_vector_type(4)));
typedef u16 u16x8 __attribute__((ext_vector_type(8)));

// Sizes fixed by reference: B=8, S=2048, I=256, H=256, M=1024
#define NX 4194304L   // key elems (16384*256)

__device__ __forceinline__ u16 f2bf(float f) {
  union { float f; uint32_t u; } v; v.f = f;
  uint32_t r = v.u + 0x7fffu + ((v.u >> 16) & 1u);
  return (u16)(r >> 16);
}

__device__ __forceinline__ u16x8 cvt8(float4 a, float4 b) {
  u16x8 o;
  o[0]=f2bf(a.x); o[1]=f2bf(a.y); o[2]=f2bf(a.z); o[3]=f2bf(a.w);
  o[4]=f2bf(b.x); o[5]=f2bf(b.y); o[6]=f2bf(b.z); o[7]=f2bf(b.w);
  return o;
}

// LDS layout for the 128x256 bf16 B-tile (exactly 64 KB):
//   addr_elems(row, k) = row*256 + (((k>>3) ^ (row&7)) << 3) + (k&7)
// 16B-chunk XOR swizzle -> every wave64 b128 read/write lands at the
// 8-cycle LDS bandwidth floor (no pathological same-bank pile-up),
// and all accesses stay 16B-aligned (ds_read_b128-safe).
__device__ __forceinline__ int sw_addr(int row, int k) {
  return row * 256 + ((((k >> 3) ^ (row & 7)) << 3)) + (k & 7);
}

// Barrier-free-K-loop NT GEMM: C[M,N] = op(A[M,K] * B[N,K]^T), K=256.
// B (fp32) is staged ONCE to LDS with fused fp32->bf16 conversion; the
// K-loop has no __syncthreads(), A-fragments load straight from global
// in MFMA fragment layout (16B/lane contiguous), so the compiler can
// issue global loads arbitrarily early relative to the MFMAs.
// 128x128 tile, 256 threads (2x2 waves of 64x64), 16x16x32 bf16 MFMA.
template<bool A_BF16, bool RELU, bool STORE_BF16>
__global__ __launch_bounds__(256, 2)
void gemm_direct(const void* __restrict__ Ap, const float* __restrict__ Bp,
                 float* __restrict__ C, u16* __restrict__ Cbf, int N,
                 long sA_batch, long sB_batch, long sC_batch)
{
  constexpr int K = 256;
  __shared__ __align__(16) u16 sB[128 * 256];   // 64 KB

  const int tid  = threadIdx.x;
  const int wave = tid >> 6;
  const int lane = tid & 63;
  const int quad = lane >> 4;
  const int r    = lane & 15;
  const int wm   = wave >> 1;
  const int wn   = wave & 1;
  const int bm   = blockIdx.y * 128;
  const int bn   = blockIdx.x * 128;
  const int batch = blockIdx.z;

  // ---- stage whole B tile (128 rows x K=256), fp32 -> bf16, once ----
  {
    const int rowS = tid >> 1;           // 0..127
    const int colS = (tid & 1) * 16;     // 0 or 16
    const float* Bg = Bp + (long)batch * sB_batch + (long)(bn + rowS) * K + colS;
    #pragma unroll
    for (int c = 0; c < 8; ++c) {
      const float* p = Bg + c * 32;
      float4 f0 = *(const float4*)(p);
      float4 f1 = *(const float4*)(p + 4);
      float4 f2 = *(const float4*)(p + 8);
      float4 f3 = *(const float4*)(p + 12);
      u16x8 lo = cvt8(f0, f1);
      u16x8 hi = cvt8(f2, f3);
      const int col = colS + c * 32;
      *(u16x8*)(sB + sw_addr(rowS, col))     = lo;
      *(u16x8*)(sB + sw_addr(rowS, col + 8)) = hi;
    }
  }
  __syncthreads();   // the only barrier in the kernel

  const float* Af = nullptr;
  const u16*   Ah = nullptr;
  if (A_BF16) Ah = (const u16*)Ap   + (long)batch * sA_batch + (long)(bm + wm * 64 + r) * K;
  else        Af = (const float*)Ap + (long)batch * sA_batch + (long)(bm + wm * 64 + r) * K;

  f32x4 acc[4][4];
  #pragma unroll
  for (int i = 0; i < 4; i++)
    #pragma unroll
    for (int j = 0; j < 4; j++)
      acc[i][j] = f32x4{0.f, 0.f, 0.f, 0.f};

  #pragma unroll 2
  for (int kt = 0; kt < K; kt += 32) {
    bf16x8 af[4], bf[4];
    // A-fragments: A[m = lane&15][k = quad*8 + j], 16B contiguous per lane
    #pragma unroll
    for (int i = 0; i < 4; ++i) {
      if (A_BF16) {
        af[i] = *(const bf16x8*)(Ah + (long)i * 16 * K + kt + quad * 8);
      } else {
        const float* p = Af + (long)i * 16 * K + kt + quad * 8;
        float4 a0 = *(const float4*)(p);
        float4 a1 = *(const float4*)(p + 4);
        u16x8 t = cvt8(a0, a1);
        af[i] = *(bf16x8*)&t;
      }
    }
    // B-fragments from swizzled LDS: B^T[n = lane&15][k = quad*8 + j]
    #pragma unroll
    for (int j = 0; j < 4; ++j)
      bf[j] = *(const bf16x8*)(sB + sw_addr(wn * 64 + j * 16 + r, kt + quad * 8));
    #pragma unroll
    for (int i = 0; i < 4; ++i)
      #pragma unroll
      for (int j = 0; j < 4; ++j)
        acc[i][j] = __builtin_amdgcn_mfma_f32_16x16x32_bf16(af[i], bf[j], acc[i][j], 0, 0, 0);
  }

  // epilogue: C/D layout col=lane&15, row=quad*4+reg (verified m89/m91)
  float* Co = C + (long)batch * sC_batch;
  u16*   Bo = STORE_BF16 ? (Cbf + (long)batch * sC_batch) : nullptr;
  #pragma unroll
  for (int i = 0; i < 4; i++) {
    #pragma unroll
    for (int j = 0; j < 4; j++) {
      #pragma unroll
      for (int reg = 0; reg < 4; reg++) {
        const int row = bm + wm * 64 + i * 16 + quad * 4 + reg;
        const int col = bn + wn * 64 + j * 16 + r;
        float v = acc[i][j][reg];
        if (RELU) v = v > 0.f ? v : 0.f;
        const long idx = (long)row * N + col;
        Co[idx] = v;
        if (STORE_BF16) Bo[idx] = f2bf(v);
      }
    }
  }
}

extern "C" void kernel_launch(void* const* d_in, const int* in_sizes, int n_in,
                              void* d_out, int out_size, void* d_ws, size_t ws_size,
                              hipStream_t stream) {
  const float* x   = (const float*)d_in[0];  // (8,2048,256) -> (16384,256)
  const float* mem = (const float*)d_in[1];  // (8,1024,256)
  const float* W   = (const float*)d_in[2];  // (256,256)
  float* out   = (float*)d_out;
  float* key_f = out;            // (16384,256) fp32
  float* val_f = out + NX;       // (8,2048,1024) fp32
  u16* key_bf  = (u16*)d_ws;     // (16384,256) bf16, 8.4 MB

  // 1) key = relu(x @ W^T): M=16384, N=256, K=256.
  //    A = x fp32 (direct frag loads + cvt), B = W fp32 (staged+cvt once).
  //    Dual-store: fp32 -> d_out, bf16 -> ws.
  dim3 g1(2, 128, 1);
  gemm_direct<false, true, true><<<g1, 256, 0, stream>>>(
      (const void*)x, W, key_f, key_bf, 256, 0, 0, 0);

  // 2) val_b = key_b @ mem_b^T: per batch M=2048, N=1024, K=256.
  //    A = key bf16 from ws (direct frag loads), B = mem fp32 (staged+cvt once).
  dim3 g2(8, 16, 8);
  gemm_direct<true, false, false><<<g2, 256, 0, stream>>>(
      (const void*)key_bf, mem, val_f, nullptr, 1024,
      (long)2048 * 256, (long)1024 * 256, (long)2048 * 1024);
}